// Round 17
// baseline (612.214 us; speedup 1.0000x reference)
//
#include <hip/hip_runtime.h>
#include <hip/hip_bf16.h>
#include <math.h>

#define BD 8        // batch
#define TD 1024     // T
#define CD 1024     // C
#define PD 100      // patterns
#define KS 16       // K-split for hidden GEMMs
#define KW (CD / KS)   // 64
#define TT (TD * TD)
#define NBLK 1024   // grid size; co-resident: 4 blocks/CU x 256 CU
#define LAMBDA 0.1f
#define SIM_THR 0.5f

typedef float f4 __attribute__((ext_vector_type(4)));

// -------- device-global scratch (fully rewritten each call; deterministic) --
__device__ float g_pctx[KS][BD][CD];   // k-partials of context hidden
__device__ float g_ptrg[KS][PD][CD];   // k-partials of trigger hidden
__device__ float g_ctxb[BD][CD];       // b1 + sum_kz pctx  (final)
__device__ float g_trgh[PD][CD];       // sum_kz ptrg       (final)
__device__ float g_wd[PD];             // dense gated weights, lambda folded in
__device__ unsigned long long g_bar[3];  // monotonic barrier counters
// g_bar never reset: each call adds exactly NBLK per barrier; generation is
// old/NBLK -> identical behavior on every graph replay. u64: no overflow.

// Grid barrier: all NBLK blocks arrive (device-scope release add), spin on a
// device-scope acquire LOAD (no RMW contention). Bounded spin converts any
// co-residency failure into a fast wrong-answer instead of a hang.
__device__ __forceinline__ void grid_barrier(int i) {
    __syncthreads();
    if (threadIdx.x == 0) {
        __threadfence();
        const unsigned long long old =
            __hip_atomic_fetch_add(&g_bar[i], 1ull, __ATOMIC_ACQ_REL,
                                   __HIP_MEMORY_SCOPE_AGENT);
        const unsigned long long target = (old / NBLK + 1ull) * NBLK;
        int polls = 0;
        while (__hip_atomic_load(&g_bar[i], __ATOMIC_ACQUIRE,
                                 __HIP_MEMORY_SCOPE_AGENT) < target) {
            __builtin_amdgcn_s_sleep(1);
            if (++polls > (1 << 20)) break;    // ~0.1 s cap: fail fast, no hang
        }
        __threadfence();
    }
    __syncthreads();
}

// -------- fused: hidden -> sums -> score -> out (phases = R15 kernels) ------
__global__ __launch_bounds__(256, 4) void fused_kernel(const float* __restrict__ attn,
                                                       const float* __restrict__ context,
                                                       const float* __restrict__ triggers,
                                                       const float* __restrict__ biases,
                                                       const float* __restrict__ conf,
                                                       const float* __restrict__ W1,
                                                       const float* __restrict__ b1,
                                                       const float* __restrict__ W2,
                                                       const float* __restrict__ b2,
                                                       float* __restrict__ out) {
    const int flat = blockIdx.x;
    const int tid  = threadIdx.x;

    __shared__ float    s_src[10][KW];     // phase 1
    __shared__ float    s_logit[BD];       // phase 3
    __shared__ float    s_w[PD];           // phase 4
    __shared__ unsigned s_off[PD];
    __shared__ int      s_n;

    // ===== phase 1: hidden partials (blocks 0..703 = old grid 4x11x16) ======
    if (flat < 704) {
        const int kz  = flat / 44;
        const int rem = flat - kz * 44;
        const int yy  = rem >> 2;            // 0..10
        const int xx  = rem & 3;             // 0..3
        const int c   = xx * 256 + tid;
        const int k0  = kz * KW;
        const bool is_ctx = (yy == 0);
        const int  ych = yy - 1;
        const float* __restrict__ W1p = is_ctx ? W1 : (W1 + (size_t)CD * CD);
        const float* __restrict__ src = is_ctx ? context : (triggers + (size_t)ych * 10 * CD);
        float* __restrict__ dst = is_ctx ? &g_pctx[kz][0][0] : &g_ptrg[kz][ych * 10][0];
        const int nrows = is_ctx ? 8 : 10;

        for (int t = tid; t < 10 * KW; t += 256) {
            const int r = t >> 6, k = t & (KW - 1);
            s_src[r][k] = src[(size_t)(r < nrows ? r : 0) * CD + k0 + k];
        }
        __syncthreads();

        float acc[10];
#pragma unroll
        for (int i = 0; i < 10; ++i) acc[i] = 0.f;

#pragma unroll 8
        for (int kk = 0; kk < KW; ++kk) {
            const float wv = W1p[(size_t)(k0 + kk) * CD + c];
#pragma unroll
            for (int i = 0; i < 10; ++i)
                acc[i] = fmaf(s_src[i][kk], wv, acc[i]);
        }
#pragma unroll
        for (int i = 0; i < 10; ++i)
            if (i < nrows) dst[(size_t)i * CD + c] = acc[i];
    }
    grid_barrier(0);

    // ===== phase 2: final sums (blocks 0..431, = R15 sum_kernel) ============
    if (flat < 32) {
        const int idx = flat * 256 + tid;                 // 0..8191
        const int b = idx >> 10, c = idx & (CD - 1);
        float v = b1[c];
#pragma unroll
        for (int kz = 0; kz < KS; ++kz) v += g_pctx[kz][b][c];
        g_ctxb[b][c] = v;
    } else if (flat < 432) {
        const int idx = (flat - 32) * 256 + tid;          // 0..102399
        const int p = idx >> 10, c = idx & (CD - 1);
        float v = 0.f;
#pragma unroll
        for (int kz = 0; kz < KS; ++kz) v += g_ptrg[kz][p][c];
        g_trgh[p][c] = v;
    }
    grid_barrier(1);

    // ===== phase 3: score (blocks 0..99); wave w handles rows 2w, 2w+1 ======
    if (flat < PD) {
        const int p = flat;
        const int wv = tid >> 6, lane = tid & 63;
#pragma unroll
        for (int bb = 0; bb < 2; ++bb) {
            const int b = wv * 2 + bb;
            float sum = 0.f;
            for (int c = lane; c < CD; c += 64) {
                const float v = g_trgh[p][c] + g_ctxb[b][c];
                sum = fmaf(fmaxf(v, 0.f), W2[c], sum);
            }
#pragma unroll
            for (int off = 32; off > 0; off >>= 1) sum += __shfl_down(sum, off);
            if (lane == 0) s_logit[b] = sum + b2[0];
        }
        __syncthreads();
        if (tid == 0) {
            float s = 0.f;
#pragma unroll
            for (int bb = 0; bb < BD; ++bb) s += 1.f / (1.f + expf(-s_logit[bb]));
            s *= (1.f / BD);
            g_wd[p] = (s > SIM_THR) ? s * conf[p] * LAMBDA : 0.f;
        }
    }
    grid_barrier(2);

    // ===== phase 4: out = attn + sum_t w[t]*biases[idx[t]] (R15 verbatim) ===
    if (tid < 64) {                          // wave 0: parallel compaction
        const int lane = tid;
        const float w0 = g_wd[lane];
        const float w1 = (lane < PD - 64) ? g_wd[lane + 64] : 0.f;
        const unsigned long long m0 = __ballot(w0 != 0.f);
        const unsigned long long m1 = __ballot(w1 != 0.f);
        const unsigned long long below = (1ull << lane) - 1;
        const int c0 = __popcll(m0);
        if (w0 != 0.f) {
            const int i = __popcll(m0 & below);
            s_w[i] = w0; s_off[i] = (unsigned)(lane * TT);
        }
        if (w1 != 0.f) {
            const int i = c0 + __popcll(m1 & below);
            s_w[i] = w1; s_off[i] = (unsigned)((lane + 64) * TT);
        }
        if (lane == 0) s_n = c0 + __popcll(m1);
    }
    __syncthreads();
    const int n = s_n;

    const size_t seg = (size_t)flat * 1024 + (size_t)tid * 4;

    f4 acc = {0.f, 0.f, 0.f, 0.f};
    int t = 0;
    for (; t + 8 <= n; t += 8) {
        float w[8];
        f4 v[8];
#pragma unroll
        for (int u = 0; u < 8; ++u) w[u] = s_w[t + u];
#pragma unroll
        for (int u = 0; u < 8; ++u)
            v[u] = *(const f4*)(biases + (size_t)s_off[t + u] + seg);
#pragma unroll
        for (int u = 0; u < 8; ++u) {
            acc.x = fmaf(w[u], v[u].x, acc.x);
            acc.y = fmaf(w[u], v[u].y, acc.y);
            acc.z = fmaf(w[u], v[u].z, acc.z);
            acc.w = fmaf(w[u], v[u].w, acc.w);
        }
    }
    for (; t < n; ++t) {
        const float w = s_w[t];
        const f4 bv = *(const f4*)(biases + (size_t)s_off[t] + seg);
        acc.x = fmaf(w, bv.x, acc.x);
        acc.y = fmaf(w, bv.y, acc.y);
        acc.z = fmaf(w, bv.z, acc.z);
        acc.w = fmaf(w, bv.w, acc.w);
    }

#pragma unroll
    for (int b = 0; b < BD; ++b) {
        const size_t off = (size_t)b * TT + seg;
        const f4 av = *(const f4*)(attn + off);
        __builtin_nontemporal_store(av + acc, (f4*)(out + off));
    }
}

extern "C" void kernel_launch(void* const* d_in, const int* in_sizes, int n_in,
                              void* d_out, int out_size, void* d_ws, size_t ws_size,
                              hipStream_t stream) {
    const float* attn     = (const float*)d_in[0];  // (B,T,T)
    const float* context  = (const float*)d_in[1];  // (B,C)
    const float* triggers = (const float*)d_in[2];  // (P,C)
    const float* biases   = (const float*)d_in[3];  // (P,T,T)
    const float* conf     = (const float*)d_in[4];  // (P,)
    const float* W1       = (const float*)d_in[5];  // (2C,C)
    const float* b1       = (const float*)d_in[6];  // (C,)
    const float* W2       = (const float*)d_in[7];  // (C,)
    const float* b2       = (const float*)d_in[8];  // (1,)
    float* out = (float*)d_out;

    hipLaunchKernelGGL(fused_kernel, dim3(NBLK), dim3(256), 0, stream,
                       attn, context, triggers, biases, conf, W1, b1, W2, b2, out);
}

// Round 18
// 122.182 us; speedup vs baseline: 5.0107x; 5.0107x over previous
//
#include <hip/hip_runtime.h>
#include <hip/hip_bf16.h>
#include <math.h>

#define BD 8        // batch
#define TD 1024     // T
#define CD 1024     // C
#define PD 100      // patterns
#define KS 16       // K-split for hidden GEMMs
#define KW (CD / KS)   // 64
#define NR 20       // trigger rows per block (5 chunks)
#define TT (TD * TD)
#define LAMBDA 0.1f
#define SIM_THR 0.5f

typedef float f4 __attribute__((ext_vector_type(4)));

// -------- device-global scratch (fully rewritten each call; deterministic) --
__device__ float g_pctx[KS][BD][CD];   // k-partials of context hidden
__device__ float g_ptrg[KS][PD][CD];   // k-partials of trigger hidden
__device__ float g_ctxb[BD][CD];       // b1 + sum_kz pctx  (final)
__device__ float g_trgh[PD][CD];       // sum_kz ptrg       (final)
__device__ float g_wd[PD];             // dense gated weights, lambda folded in

// -------- K1: partial hidden = X @ W1part over a 64-wide K slice -----------
// grid = (4, 6, KS): y==0 -> context (8 rows), y=1..5 -> 20-row trigger chunk.
// 20 rows/block: W1[C:] re-read 5x (was 10x) and 20 FMAs per W1 load.
__global__ __launch_bounds__(256) void hidden_kernel(const float* __restrict__ context,
                                                     const float* __restrict__ triggers,
                                                     const float* __restrict__ W1) {
    const int c  = blockIdx.x * 256 + threadIdx.x;   // output column
    const int kz = blockIdx.z;
    const int k0 = kz * KW;
    const bool is_ctx = (blockIdx.y == 0);
    const int  ych = blockIdx.y - 1;                 // trigger chunk 0..4
    const float* __restrict__ W1p = is_ctx ? W1 : (W1 + (size_t)CD * CD);
    const float* __restrict__ src = is_ctx ? context : (triggers + (size_t)ych * NR * CD);
    float* __restrict__ dst = is_ctx ? &g_pctx[kz][0][0] : &g_ptrg[kz][ych * NR][0];
    const int nrows = is_ctx ? 8 : NR;

    __shared__ float s_src[NR][KW];
    for (int t = threadIdx.x; t < NR * KW; t += 256) {
        const int r = t >> 6, k = t & (KW - 1);
        s_src[r][k] = src[(size_t)(r < nrows ? r : 0) * CD + k0 + k];
    }
    __syncthreads();

    float acc[NR];
#pragma unroll
    for (int i = 0; i < NR; ++i) acc[i] = 0.f;

#pragma unroll 8
    for (int kk = 0; kk < KW; ++kk) {
        const float wv = W1p[(size_t)(k0 + kk) * CD + c];
#pragma unroll
        for (int i = 0; i < NR; ++i)
            acc[i] = fmaf(s_src[i][kk], wv, acc[i]);
    }
#pragma unroll
    for (int i = 0; i < NR; ++i)
        if (i < nrows) dst[(size_t)i * CD + c] = acc[i];
}

// -------- K2: final sums — ctx rows (+b1) and trigger rows ------------------
// grid = (32 + 400): blocks 0..31 -> g_ctxb (8x1024), 32..431 -> g_trgh.
__global__ __launch_bounds__(256) void sum_kernel(const float* __restrict__ b1) {
    if (blockIdx.x < 32) {
        const int idx = blockIdx.x * 256 + threadIdx.x;   // 0..8191
        const int b = idx >> 10, c = idx & (CD - 1);
        float v = b1[c];
#pragma unroll
        for (int kz = 0; kz < KS; ++kz) v += g_pctx[kz][b][c];
        g_ctxb[b][c] = v;
    } else {
        const int idx = (blockIdx.x - 32) * 256 + threadIdx.x;  // 0..102399
        const int p = idx >> 10, c = idx & (CD - 1);
        float v = 0.f;
#pragma unroll
        for (int kz = 0; kz < KS; ++kz) v += g_ptrg[kz][p][c];
        g_trgh[p][c] = v;
    }
}

// -------- K3: per-pattern score from final sums (light) ---------------------
// grid = (PD), block 512: wave w handles batch row b=w.
__global__ __launch_bounds__(512) void score_kernel(const float* __restrict__ W2,
                                                    const float* __restrict__ b2,
                                                    const float* __restrict__ conf) {
    const int p = blockIdx.x;
    __shared__ float s_logit[BD];

    const int b = threadIdx.x >> 6, lane = threadIdx.x & 63;
    float sum = 0.f;
    for (int c = lane; c < CD; c += 64) {
        const float v = g_trgh[p][c] + g_ctxb[b][c];
        sum = fmaf(fmaxf(v, 0.f), W2[c], sum);
    }
#pragma unroll
    for (int off = 32; off > 0; off >>= 1) sum += __shfl_down(sum, off);
    if (lane == 0) s_logit[b] = sum + b2[0];
    __syncthreads();
    if (threadIdx.x == 0) {
        float s = 0.f;
#pragma unroll
        for (int bb = 0; bb < BD; ++bb) s += 1.f / (1.f + expf(-s_logit[bb]));
        s *= (1.f / BD);
        g_wd[p] = (s > SIM_THR) ? s * conf[p] * LAMBDA : 0.f;
    }
}

// -------- K4: out = attn + sum_t w[t]*biases[idx[t]]  (pattern-innermost) ---
// grid = (1024) x 256 thr: thread owns one f4 of the (T,T) plane; 8-deep
// pattern unroll; cacheable loads; nontemporal stores; ballot compaction.
__global__ __launch_bounds__(256) void out_kernel(const float* __restrict__ attn,
                                                  const float* __restrict__ biases,
                                                  float* __restrict__ out) {
    __shared__ float    s_w[PD];
    __shared__ unsigned s_off[PD];
    __shared__ int      s_n;

    if (threadIdx.x < 64) {                 // wave 0: parallel compaction
        const int lane = threadIdx.x;
        const float w0 = g_wd[lane];
        const float w1 = (lane < PD - 64) ? g_wd[lane + 64] : 0.f;
        const unsigned long long m0 = __ballot(w0 != 0.f);
        const unsigned long long m1 = __ballot(w1 != 0.f);
        const unsigned long long below = (1ull << lane) - 1;
        const int c0 = __popcll(m0);
        if (w0 != 0.f) {
            const int i = __popcll(m0 & below);
            s_w[i] = w0; s_off[i] = (unsigned)(lane * TT);
        }
        if (w1 != 0.f) {
            const int i = c0 + __popcll(m1 & below);
            s_w[i] = w1; s_off[i] = (unsigned)((lane + 64) * TT);
        }
        if (lane == 0) s_n = c0 + __popcll(m1);
    }
    __syncthreads();
    const int n = s_n;

    const size_t seg = (size_t)blockIdx.x * 1024 + (size_t)threadIdx.x * 4;

    f4 acc = {0.f, 0.f, 0.f, 0.f};
    int t = 0;
    for (; t + 8 <= n; t += 8) {
        float w[8];
        f4 v[8];
#pragma unroll
        for (int u = 0; u < 8; ++u) w[u] = s_w[t + u];
#pragma unroll
        for (int u = 0; u < 8; ++u)
            v[u] = *(const f4*)(biases + (size_t)s_off[t + u] + seg);
#pragma unroll
        for (int u = 0; u < 8; ++u) {
            acc.x = fmaf(w[u], v[u].x, acc.x);
            acc.y = fmaf(w[u], v[u].y, acc.y);
            acc.z = fmaf(w[u], v[u].z, acc.z);
            acc.w = fmaf(w[u], v[u].w, acc.w);
        }
    }
    for (; t < n; ++t) {
        const float w = s_w[t];
        const f4 bv = *(const f4*)(biases + (size_t)s_off[t] + seg);
        acc.x = fmaf(w, bv.x, acc.x);
        acc.y = fmaf(w, bv.y, acc.y);
        acc.z = fmaf(w, bv.z, acc.z);
        acc.w = fmaf(w, bv.w, acc.w);
    }

#pragma unroll
    for (int b = 0; b < BD; ++b) {
        const size_t off = (size_t)b * TT + seg;
        const f4 av = *(const f4*)(attn + off);
        __builtin_nontemporal_store(av + acc, (f4*)(out + off));
    }
}

extern "C" void kernel_launch(void* const* d_in, const int* in_sizes, int n_in,
                              void* d_out, int out_size, void* d_ws, size_t ws_size,
                              hipStream_t stream) {
    const float* attn     = (const float*)d_in[0];  // (B,T,T)
    const float* context  = (const float*)d_in[1];  // (B,C)
    const float* triggers = (const float*)d_in[2];  // (P,C)
    const float* biases   = (const float*)d_in[3];  // (P,T,T)
    const float* conf     = (const float*)d_in[4];  // (P,)
    const float* W1       = (const float*)d_in[5];  // (2C,C)
    const float* b1       = (const float*)d_in[6];  // (C,)
    const float* W2       = (const float*)d_in[7];  // (C,)
    const float* b2       = (const float*)d_in[8];  // (1,)
    float* out = (float*)d_out;

    hipLaunchKernelGGL(hidden_kernel, dim3(4, 6, KS), dim3(256), 0, stream,
                       context, triggers, W1);
    hipLaunchKernelGGL(sum_kernel, dim3(32 + 400), dim3(256), 0, stream, b1);
    hipLaunchKernelGGL(score_kernel, dim3(PD), dim3(512), 0, stream, W2, b2, conf);
    hipLaunchKernelGGL(out_kernel, dim3(TT / 1024), dim3(256), 0, stream, attn, biases, out);
}

// Round 19
// 97.326 us; speedup vs baseline: 6.2904x; 1.2554x over previous
//
#include <hip/hip_runtime.h>
#include <hip/hip_bf16.h>
#include <math.h>

#define BD 8        // batch
#define TD 1024     // T
#define CD 1024     // C
#define PD 100      // patterns
#define KS 16       // K-split for hidden GEMMs
#define KW (CD / KS)   // 64
#define TT (TD * TD)
#define LAMBDA 0.1f
#define SIM_THR 0.5f

typedef float f4 __attribute__((ext_vector_type(4)));

// -------- device-global scratch (fully rewritten each call; deterministic) --
__device__ float g_pctx[KS][BD][CD];   // k-partials of context hidden
__device__ float g_ptrg[KS][PD][CD];   // k-partials of trigger hidden
__device__ float g_ctxb[BD][CD];       // b1 + sum_kz pctx  (final)
__device__ float g_trgh[PD][CD];       // sum_kz ptrg       (final)
__device__ float g_wd[PD];             // dense gated weights, lambda folded in

// -------- K1: partial hidden = X @ W1part over a 64-wide K slice -----------
// grid = (CD/256, 11, KS): y==0 -> context (8 rows), y=1..10 -> trigger chunk
__global__ __launch_bounds__(256) void hidden_kernel(const float* __restrict__ context,
                                                     const float* __restrict__ triggers,
                                                     const float* __restrict__ W1) {
    const int c  = blockIdx.x * 256 + threadIdx.x;   // output column
    const int kz = blockIdx.z;
    const int k0 = kz * KW;
    const bool is_ctx = (blockIdx.y == 0);
    const int  ych = blockIdx.y - 1;                 // trigger chunk 0..9
    const float* __restrict__ W1p = is_ctx ? W1 : (W1 + (size_t)CD * CD);
    const float* __restrict__ src = is_ctx ? context : (triggers + (size_t)ych * 10 * CD);
    float* __restrict__ dst = is_ctx ? &g_pctx[kz][0][0] : &g_ptrg[kz][ych * 10][0];
    const int nrows = is_ctx ? 8 : 10;

    __shared__ float s_src[10][KW];
    for (int t = threadIdx.x; t < 10 * KW; t += 256) {
        const int r = t >> 6, k = t & (KW - 1);
        s_src[r][k] = src[(size_t)(r < nrows ? r : 0) * CD + k0 + k];
    }
    __syncthreads();

    float acc[10];
#pragma unroll
    for (int i = 0; i < 10; ++i) acc[i] = 0.f;

#pragma unroll 8
    for (int kk = 0; kk < KW; ++kk) {
        const float wv = W1p[(size_t)(k0 + kk) * CD + c];
#pragma unroll
        for (int i = 0; i < 10; ++i)
            acc[i] = fmaf(s_src[i][kk], wv, acc[i]);
    }
#pragma unroll
    for (int i = 0; i < 10; ++i)
        if (i < nrows) dst[(size_t)i * CD + c] = acc[i];
}

// -------- K2: final sums — ctx rows (+b1) and trigger rows ------------------
// grid = (32 + 400): blocks 0..31 -> g_ctxb (8x1024), 32..431 -> g_trgh.
__global__ __launch_bounds__(256) void sum_kernel(const float* __restrict__ b1) {
    if (blockIdx.x < 32) {
        const int idx = blockIdx.x * 256 + threadIdx.x;   // 0..8191
        const int b = idx >> 10, c = idx & (CD - 1);
        float v = b1[c];
#pragma unroll
        for (int kz = 0; kz < KS; ++kz) v += g_pctx[kz][b][c];
        g_ctxb[b][c] = v;
    } else {
        const int idx = (blockIdx.x - 32) * 256 + threadIdx.x;  // 0..102399
        const int p = idx >> 10, c = idx & (CD - 1);
        float v = 0.f;
#pragma unroll
        for (int kz = 0; kz < KS; ++kz) v += g_ptrg[kz][p][c];
        g_trgh[p][c] = v;
    }
}

// -------- K3: per-pattern score from final sums (light) ---------------------
// grid = (PD), block 512: wave w handles batch row b=w.
__global__ __launch_bounds__(512) void score_kernel(const float* __restrict__ W2,
                                                    const float* __restrict__ b2,
                                                    const float* __restrict__ conf) {
    const int p = blockIdx.x;
    __shared__ float s_logit[BD];

    const int b = threadIdx.x >> 6, lane = threadIdx.x & 63;
    float sum = 0.f;
    for (int c = lane; c < CD; c += 64) {
        const float v = g_trgh[p][c] + g_ctxb[b][c];
        sum = fmaf(fmaxf(v, 0.f), W2[c], sum);
    }
#pragma unroll
    for (int off = 32; off > 0; off >>= 1) sum += __shfl_down(sum, off);
    if (lane == 0) s_logit[b] = sum + b2[0];
    __syncthreads();
    if (threadIdx.x == 0) {
        float s = 0.f;
#pragma unroll
        for (int bb = 0; bb < BD; ++bb) s += 1.f / (1.f + expf(-s_logit[bb]));
        s *= (1.f / BD);
        g_wd[p] = (s > SIM_THR) ? s * conf[p] * LAMBDA : 0.f;
    }
}

// -------- K4: out = attn + sum_t w[t]*biases[idx[t]]  (pattern-innermost) ---
// grid = (1024) x 256 thr: thread owns one f4 of the (T,T) plane; 8-deep
// pattern unroll; cacheable loads; nontemporal stores; ballot compaction.
__global__ __launch_bounds__(256) void out_kernel(const float* __restrict__ attn,
                                                  const float* __restrict__ biases,
                                                  float* __restrict__ out) {
    __shared__ float    s_w[PD];
    __shared__ unsigned s_off[PD];
    __shared__ int      s_n;

    if (threadIdx.x < 64) {                 // wave 0: parallel compaction
        const int lane = threadIdx.x;
        const float w0 = g_wd[lane];
        const float w1 = (lane < PD - 64) ? g_wd[lane + 64] : 0.f;
        const unsigned long long m0 = __ballot(w0 != 0.f);
        const unsigned long long m1 = __ballot(w1 != 0.f);
        const unsigned long long below = (1ull << lane) - 1;
        const int c0 = __popcll(m0);
        if (w0 != 0.f) {
            const int i = __popcll(m0 & below);
            s_w[i] = w0; s_off[i] = (unsigned)(lane * TT);
        }
        if (w1 != 0.f) {
            const int i = c0 + __popcll(m1 & below);
            s_w[i] = w1; s_off[i] = (unsigned)((lane + 64) * TT);
        }
        if (lane == 0) s_n = c0 + __popcll(m1);
    }
    __syncthreads();
    const int n = s_n;

    const size_t seg = (size_t)blockIdx.x * 1024 + (size_t)threadIdx.x * 4;

    f4 acc = {0.f, 0.f, 0.f, 0.f};
    int t = 0;
    for (; t + 8 <= n; t += 8) {
        float w[8];
        f4 v[8];
#pragma unroll
        for (int u = 0; u < 8; ++u) w[u] = s_w[t + u];
#pragma unroll
        for (int u = 0; u < 8; ++u)
            v[u] = *(const f4*)(biases + (size_t)s_off[t + u] + seg);
#pragma unroll
        for (int u = 0; u < 8; ++u) {
            acc.x = fmaf(w[u], v[u].x, acc.x);
            acc.y = fmaf(w[u], v[u].y, acc.y);
            acc.z = fmaf(w[u], v[u].z, acc.z);
            acc.w = fmaf(w[u], v[u].w, acc.w);
        }
    }
    for (; t < n; ++t) {
        const float w = s_w[t];
        const f4 bv = *(const f4*)(biases + (size_t)s_off[t] + seg);
        acc.x = fmaf(w, bv.x, acc.x);
        acc.y = fmaf(w, bv.y, acc.y);
        acc.z = fmaf(w, bv.z, acc.z);
        acc.w = fmaf(w, bv.w, acc.w);
    }

#pragma unroll
    for (int b = 0; b < BD; ++b) {
        const size_t off = (size_t)b * TT + seg;
        const f4 av = *(const f4*)(attn + off);
        __builtin_nontemporal_store(av + acc, (f4*)(out + off));
    }
}

extern "C" void kernel_launch(void* const* d_in, const int* in_sizes, int n_in,
                              void* d_out, int out_size, void* d_ws, size_t ws_size,
                              hipStream_t stream) {
    const float* attn     = (const float*)d_in[0];  // (B,T,T)
    const float* context  = (const float*)d_in[1];  // (B,C)
    const float* triggers = (const float*)d_in[2];  // (P,C)
    const float* biases   = (const float*)d_in[3];  // (P,T,T)
    const float* conf     = (const float*)d_in[4];  // (P,)
    const float* W1       = (const float*)d_in[5];  // (2C,C)
    const float* b1       = (const float*)d_in[6];  // (C,)
    const float* W2       = (const float*)d_in[7];  // (C,)
    const float* b2       = (const float*)d_in[8];  // (1,)
    float* out = (float*)d_out;

    hipLaunchKernelGGL(hidden_kernel, dim3(CD / 256, 11, KS), dim3(256), 0, stream,
                       context, triggers, W1);
    hipLaunchKernelGGL(sum_kernel, dim3(32 + 400), dim3(256), 0, stream, b1);
    hipLaunchKernelGGL(score_kernel, dim3(PD), dim3(512), 0, stream, W2, b2, conf);
    hipLaunchKernelGGL(out_kernel, dim3(TT / 1024), dim3(256), 0, stream, attn, biases, out);
}